// Round 7
// baseline (158.613 us; speedup 1.0000x reference)
//
#include <hip/hip_runtime.h>
#include <cstddef>

// Problem constants
#define BB 4
#define CCH 256     // C
#define C2 128      // C/2
#define NN 4096     // T*H*W
#define PM 384      // 3*C2
#define KVS 16      // split-K slices for K*V^T (256 n each)

typedef __attribute__((ext_vector_type(8))) short short8v;   // 8 bf16
typedef __attribute__((ext_vector_type(4))) short short4v;   // 4 bf16
typedef __attribute__((ext_vector_type(4))) float f32x4;

static __device__ __forceinline__ short f2bf(float f) {
    union { float f; unsigned u; } c; c.f = f;
    unsigned r = (c.u + 0x7FFFu + ((c.u >> 16) & 1u)) >> 16;
    return (short)r;
}

// ---------------- prep: XpH = bf16(X+pe); pack W/Wo bf16 + biases -----------
__global__ __launch_bounds__(256) void k_prep(
    const float* __restrict__ X, const float* __restrict__ pe,
    const float* __restrict__ Wq, const float* __restrict__ bq,
    const float* __restrict__ Wk, const float* __restrict__ bk,
    const float* __restrict__ Wv, const float* __restrict__ bv,
    const float* __restrict__ Wo,
    short* __restrict__ XpH, short* __restrict__ wpackh,
    float* __restrict__ bpack, short* __restrict__ Woh)
{
    const int blk = blockIdx.x;
    if (blk < 2048) {
        const size_t e8 = ((size_t)blk * 256 + threadIdx.x) * 8;
        const size_t r  = e8 & (size_t)(CCH * NN - 1);
        float4 x0 = *(const float4*)&X[e8];
        float4 x1 = *(const float4*)&X[e8 + 4];
        float4 p0 = *(const float4*)&pe[r];
        float4 p1 = *(const float4*)&pe[r + 4];
        short8v o;
        o[0] = f2bf(x0.x + p0.x); o[1] = f2bf(x0.y + p0.y);
        o[2] = f2bf(x0.z + p0.z); o[3] = f2bf(x0.w + p0.w);
        o[4] = f2bf(x1.x + p1.x); o[5] = f2bf(x1.y + p1.y);
        o[6] = f2bf(x1.z + p1.z); o[7] = f2bf(x1.w + p1.w);
        *(short8v*)&XpH[e8] = o;
    } else {
        const int m = blk - 2048;     // 0..639
        const int c = threadIdx.x;
        if (m < PM) {
            const float* w; const float* bs; int mm;
            if (m < C2)        { w = Wq; bs = bq; mm = m; }
            else if (m < 2*C2) { w = Wk; bs = bk; mm = m - C2; }
            else               { w = Wv; bs = bv; mm = m - 2*C2; }
            wpackh[m * CCH + c] = f2bf(w[mm * CCH + c]);
            if (c == 0) bpack[m] = bs[mm];
        } else {
            const int o = m - PM;     // 0..255
            if (c < C2) Woh[o * C2 + c] = f2bf(Wo[o * C2 + c]);
        }
    }
}

// ---------------- QKV projection (bf16 MFMA) --------------------------------
// qkv[m][n] = sum_c W[m][c]*Xp[c][n] + bias[m] + task[m%128][n]
// A direct from global (L2-resident, pipelined); only B staged via LDS.
// Outputs: sel0 -> qg[b][g][crow][i] (g=n&31, crow=n>>5), sel1 -> kk[b][i][n],
// sel2 -> vv[b][i][n].
#define LROW 40
#define TSP  136
__global__ __launch_bounds__(256) void k_projm(
    const short* __restrict__ XpH,
    const float* __restrict__ tq, const float* __restrict__ tk,
    const float* __restrict__ tv,
    const short* __restrict__ wpackh, const float* __restrict__ bpack,
    short* __restrict__ qg, short* __restrict__ kk, short* __restrict__ vv)
{
    __shared__ short smem[17408];      // Bs (10240) ; epilogue Ts (17408)
    short* Bs = smem;                  // [128 n][40] bf16 ([n][k] of Xp)
    const int b  = blockIdx.z;
    const int m0 = blockIdx.y * 128;   // 0,128,256
    const int n0 = blockIdx.x * 128;
    const int tid  = threadIdx.x;
    const int wave = tid >> 6;
    const int lane = tid & 63;
    const int lr = lane & 15, lg = lane >> 4;
    const int wm = wave >> 1, wn = wave & 1;   // 2x2 wave grid, 64x64 each
    const short* __restrict__ Xb = XpH + (size_t)b * CCH * NN;

    const int cq = tid >> 5;          // B stage: c-quad
    const int nq = tid & 31;          // B stage: n-quad

    // A fragment row base addresses (per fm)
    const short* Arow[4];
#pragma unroll
    for (int fm = 0; fm < 4; ++fm)
        Arow[fm] = wpackh + (size_t)(m0 + wm * 64 + fm * 16 + lr) * CCH + lg * 8;

    f32x4 acc[4][4];
#pragma unroll
    for (int i = 0; i < 4; ++i)
#pragma unroll
        for (int j = 0; j < 4; ++j) acc[i][j] = (f32x4){0.f, 0.f, 0.f, 0.f};

    short8v a_cur[4], a_nxt[4];
#pragma unroll
    for (int fm = 0; fm < 4; ++fm) a_cur[fm] = *(const short8v*)&Arow[fm][0];

    for (int k0 = 0; k0 < CCH; k0 += 32) {
        // stage B: transpose 32c x 128n of XpH -> [n][k]
        short sreg[4][4];
#pragma unroll
        for (int j = 0; j < 4; ++j) {
            const int c = k0 + cq * 4 + j;
            short4v xv = *(const short4v*)&Xb[(size_t)c * NN + n0 + nq * 4];
            sreg[j][0] = xv.x; sreg[j][1] = xv.y; sreg[j][2] = xv.z; sreg[j][3] = xv.w;
        }
#pragma unroll
        for (int i = 0; i < 4; ++i) {
            short4v v; v.x = sreg[0][i]; v.y = sreg[1][i]; v.z = sreg[2][i]; v.w = sreg[3][i];
            *(short4v*)&Bs[(nq * 4 + i) * LROW + cq * 4] = v;
        }
        __syncthreads();
        // prefetch next A fragments (independent of LDS)
        const bool more = (k0 + 32) < CCH;
        if (more) {
#pragma unroll
            for (int fm = 0; fm < 4; ++fm)
                a_nxt[fm] = *(const short8v*)&Arow[fm][k0 + 32];
        }
        short8v bfr[4];
#pragma unroll
        for (int fn = 0; fn < 4; ++fn)
            bfr[fn] = *(const short8v*)&Bs[(wn * 64 + fn * 16 + lr) * LROW + lg * 8];
#pragma unroll
        for (int fm = 0; fm < 4; ++fm)
#pragma unroll
            for (int fn = 0; fn < 4; ++fn)
                acc[fm][fn] = __builtin_amdgcn_mfma_f32_16x16x32_bf16(
                    a_cur[fm], bfr[fn], acc[fm][fn], 0, 0, 0);
        __syncthreads();
        if (more) {
#pragma unroll
            for (int fm = 0; fm < 4; ++fm) a_cur[fm] = a_nxt[fm];
        }
    }

    // epilogue: + bias + task, bf16, re-layout through LDS (Ts aliases Bs)
    short* Ts = smem;
    const int sel = m0 >> 7;
    if (sel == 0) {
#pragma unroll
        for (int fm = 0; fm < 4; ++fm)
#pragma unroll
            for (int fn = 0; fn < 4; ++fn) {
                const int n_l  = wn * 64 + fn * 16 + lr;
                const int m_lb = wm * 64 + fm * 16 + lg * 4;
                short4v v;
#pragma unroll
                for (int r = 0; r < 4; ++r) {
                    const int m_l = m_lb + r;
                    v[r] = f2bf(acc[fm][fn][r] + bpack[m_l]
                                + tq[(size_t)m_l * NN + n0 + n_l]);
                }
                *(short4v*)&Ts[n_l * TSP + m_lb] = v;
            }
        __syncthreads();
        const int n_l = tid >> 1, half = tid & 1;
        const int n = n0 + n_l;
        short* dst = qg + (size_t)b * NN * C2
                   + ((size_t)(n & 31) * 128 + (n >> 5)) * C2 + half * 64;
        const short* src = &Ts[n_l * TSP + half * 64];
#pragma unroll
        for (int q2 = 0; q2 < 8; ++q2)
            *(short8v*)&dst[q2 * 8] = *(const short8v*)&src[q2 * 8];
    } else {
        const float* __restrict__ task = (sel == 1) ? tk : tv;
        short* kv = (sel == 1) ? kk : vv;
#pragma unroll
        for (int fm = 0; fm < 4; ++fm)
#pragma unroll
            for (int fn = 0; fn < 4; ++fn) {
                const int n_l = wn * 64 + fn * 16 + lr;
#pragma unroll
                for (int r = 0; r < 4; ++r) {
                    const int m_l = wm * 64 + fm * 16 + lg * 4 + r;
                    Ts[m_l * TSP + n_l] =
                        f2bf(acc[fm][fn][r] + bpack[m0 + m_l]
                             + task[(size_t)m_l * NN + n0 + n_l]);
                }
            }
        __syncthreads();
        const int m_l = tid >> 1, half = tid & 1;
        short* dst = kv + (size_t)b * C2 * NN + (size_t)m_l * NN + n0 + half * 64;
        const short* src = &Ts[m_l * TSP + half * 64];
#pragma unroll
        for (int q2 = 0; q2 < 8; ++q2)
            *(short8v*)&dst[q2 * 8] = *(const short8v*)&src[q2 * 8];
    }
}

// ---------------- Mpart[b][s][j][i] = sum_{n in 256-slice s} K[i][n]*V[j][n]
// Transposed store (j rows) so k_qmfinal's reduction reads are coalesced.
__global__ __launch_bounds__(256) void k_kv(
    const short* __restrict__ kk, const short* __restrict__ vv,
    float* __restrict__ Mpart)
{
    const int b = blockIdx.y, s = blockIdx.x;
    const int tid = threadIdx.x;
    const int wave = tid >> 6, lane = tid & 63;
    const int lr = lane & 15, lg = lane >> 4;
    const int wi = wave >> 1, wj = wave & 1;
    const short* Kb = kk + (size_t)b * C2 * NN;
    const short* Vb = vv + (size_t)b * C2 * NN;
    const int nbase = s * 256;
    f32x4 acc[4][4];
#pragma unroll
    for (int i = 0; i < 4; ++i)
#pragma unroll
        for (int j = 0; j < 4; ++j) acc[i][j] = (f32x4){0.f, 0.f, 0.f, 0.f};

    for (int ks = 0; ks < 8; ++ks) {
        const int nn = nbase + ks * 32 + lg * 8;
        short8v a[4], bv8[4];
#pragma unroll
        for (int fi = 0; fi < 4; ++fi)
            a[fi] = *(const short8v*)&Kb[(size_t)(wi * 64 + fi * 16 + lr) * NN + nn];
#pragma unroll
        for (int fj = 0; fj < 4; ++fj)
            bv8[fj] = *(const short8v*)&Vb[(size_t)(wj * 64 + fj * 16 + lr) * NN + nn];
#pragma unroll
        for (int fi = 0; fi < 4; ++fi)
#pragma unroll
            for (int fj = 0; fj < 4; ++fj)
                acc[fi][fj] = __builtin_amdgcn_mfma_f32_16x16x32_bf16(
                    a[fi], bv8[fj], acc[fi][fj], 0, 0, 0);
    }
    // D: row=i (lg*4+r), col=j (lr). Store transposed: Mp[j][i], float4 over r.
    float* Mp = Mpart + ((size_t)b * KVS + s) * C2 * C2;
#pragma unroll
    for (int fi = 0; fi < 4; ++fi)
#pragma unroll
        for (int fj = 0; fj < 4; ++fj) {
            const int j = wj * 64 + fj * 16 + lr;
            const int i = wi * 64 + fi * 16 + lg * 4;
            *(float4*)&Mp[(size_t)j * C2 + i] = *(float4*)&acc[fi][fj];
        }
}

// ---------------- fused: reduce M, P = Q·M (rows n==g mod 32), out = Wo·P + X
#define MSP 136
#define PSP 136
__global__ __launch_bounds__(256) void k_qmfinal(
    const short* __restrict__ qg, const float* __restrict__ Mpart,
    const short* __restrict__ Woh,
    const float* __restrict__ X, float* __restrict__ out)
{
    __shared__ short Ms[64 * MSP];    // [j_loc][i] bf16 (reduced M, this jh half)
    __shared__ short Ps[64 * PSP];    // [j'][c] bf16
    const int g  = blockIdx.x;        // 0..31
    const int jh = blockIdx.y;        // 0..1
    const int b  = blockIdx.z;
    const int tid = threadIdx.x;
    const int wave = tid >> 6, lane = tid & 63;
    const int lr = lane & 15, lg = lane >> 4;

    // ---- phase 0: Ms[j_loc][i] = bf16( sum_s Mpart[b][s][jh*64+j_loc][i] )
    {
        const int jloc = tid >> 2;            // 0..63
        const int ib   = (tid & 3) * 4;       // 0,4,8,12 ; q strides +16
        const float* base = Mpart + (size_t)b * KVS * C2 * C2
                          + (size_t)(jh * 64 + jloc) * C2 + ib;
#pragma unroll
        for (int q = 0; q < 8; ++q) {
            float4 s0 = {0.f, 0.f, 0.f, 0.f};
            float4 s1 = {0.f, 0.f, 0.f, 0.f};
#pragma unroll
            for (int s = 0; s < KVS; s += 2) {
                float4 v0 = *(const float4*)&base[(size_t)s * C2 * C2 + q * 16];
                float4 v1 = *(const float4*)&base[(size_t)(s + 1) * C2 * C2 + q * 16];
                s0.x += v0.x; s0.y += v0.y; s0.z += v0.z; s0.w += v0.w;
                s1.x += v1.x; s1.y += v1.y; s1.z += v1.z; s1.w += v1.w;
            }
            short4v h;
            h[0] = f2bf(s0.x + s1.x); h[1] = f2bf(s0.y + s1.y);
            h[2] = f2bf(s0.z + s1.z); h[3] = f2bf(s0.w + s1.w);
            *(short4v*)&Ms[jloc * MSP + ib + q * 16] = h;
        }
    }
    __syncthreads();

    // ---- phase 1: Ps[j'][c] = sum_i qg[b][g][c][i] * M[jh*64+j'][i]
    {
        const int wc = wave >> 1, wj = wave & 1;
        const short* Qg = qg + (size_t)b * NN * C2 + (size_t)g * 128 * C2;
        f32x4 acc1[4][2];
#pragma unroll
        for (int i = 0; i < 4; ++i)
#pragma unroll
            for (int j = 0; j < 2; ++j) acc1[i][j] = (f32x4){0.f, 0.f, 0.f, 0.f};
        for (int ks = 0; ks < 4; ++ks) {
            const int kb = ks * 32 + lg * 8;
            short8v a1[4], b1[2];
#pragma unroll
            for (int fc = 0; fc < 4; ++fc)
                a1[fc] = *(const short8v*)&Qg[(size_t)(wc * 64 + fc * 16 + lr) * C2 + kb];
#pragma unroll
            for (int fj = 0; fj < 2; ++fj)
                b1[fj] = *(const short8v*)&Ms[(wj * 32 + fj * 16 + lr) * MSP + kb];
#pragma unroll
            for (int fc = 0; fc < 4; ++fc)
#pragma unroll
                for (int fj = 0; fj < 2; ++fj)
                    acc1[fc][fj] = __builtin_amdgcn_mfma_f32_16x16x32_bf16(
                        a1[fc], b1[fj], acc1[fc][fj], 0, 0, 0);
        }
        // D: row=c, col=j'. Store Ps[j'][c] (short4v along c).
#pragma unroll
        for (int fc = 0; fc < 4; ++fc)
#pragma unroll
            for (int fj = 0; fj < 2; ++fj) {
                const int jp = wj * 32 + fj * 16 + lr;
                const int c0 = wc * 64 + fc * 16 + lg * 4;
                short4v v;
#pragma unroll
                for (int r = 0; r < 4; ++r) v[r] = f2bf(acc1[fc][fj][r]);
                *(short4v*)&Ps[jp * PSP + c0] = v;
            }
    }
    __syncthreads();

    // ---- phase 2: out[o][p] = sum_c Wo[o][c] * P[c][j'] + X
    {
        f32x4 acc2[4][4];
#pragma unroll
        for (int i = 0; i < 4; ++i)
#pragma unroll
            for (int j = 0; j < 4; ++j) acc2[i][j] = (f32x4){0.f, 0.f, 0.f, 0.f};
        for (int ks = 0; ks < 4; ++ks) {
            const int kb = ks * 32 + lg * 8;
            short8v a2[4], b2[4];
#pragma unroll
            for (int fo = 0; fo < 4; ++fo)
                a2[fo] = *(const short8v*)&Woh[(size_t)(wave * 64 + fo * 16 + lr) * C2 + kb];
#pragma unroll
            for (int fj = 0; fj < 4; ++fj)
                b2[fj] = *(const short8v*)&Ps[(fj * 16 + lr) * PSP + kb];
#pragma unroll
            for (int fo = 0; fo < 4; ++fo)
#pragma unroll
                for (int fj = 0; fj < 4; ++fj)
                    acc2[fo][fj] = __builtin_amdgcn_mfma_f32_16x16x32_bf16(
                        a2[fo], b2[fj], acc2[fo][fj], 0, 0, 0);
        }
        const float* Xb = X + (size_t)b * CCH * NN;
        float* Ob = out + (size_t)b * CCH * NN;
#pragma unroll
        for (int fo = 0; fo < 4; ++fo)
#pragma unroll
            for (int fj = 0; fj < 4; ++fj) {
                const int p = g * 128 + jh * 64 + fj * 16 + lr;
                const int ob = wave * 64 + fo * 16 + lg * 4;
#pragma unroll
                for (int r = 0; r < 4; ++r) {
                    const size_t ad = (size_t)(ob + r) * NN + p;
                    Ob[ad] = acc2[fo][fj][r] + Xb[ad];
                }
            }
    }
}

extern "C" void kernel_launch(void* const* d_in, const int* in_sizes, int n_in,
                              void* d_out, int out_size, void* d_ws, size_t ws_size,
                              hipStream_t stream) {
    const float* X  = (const float*)d_in[0];
    const float* pe = (const float*)d_in[1];
    const float* tq = (const float*)d_in[2];
    const float* tk = (const float*)d_in[3];
    const float* tv = (const float*)d_in[4];
    const float* Wq = (const float*)d_in[5];
    const float* bq = (const float*)d_in[6];
    const float* Wk = (const float*)d_in[7];
    const float* bk = (const float*)d_in[8];
    const float* Wv = (const float*)d_in[9];
    const float* bv = (const float*)d_in[10];
    const float* Wo = (const float*)d_in[11];
    float* out = (float*)d_out;

    // Workspace layout (floats), ~25.5 MB total, no aliasing.
    float* ws     = (float*)d_ws;
    float* bpack  = ws;                                   // 512 f
    short* wpackh = (short*)(ws + 512);                   // 98304 sh
    short* Woh    = wpackh + (size_t)PM * CCH;            // 32768 sh
    short* XpH    = Woh + (size_t)CCH * C2;               // 4194304 sh
    short* qg     = XpH + (size_t)BB * CCH * NN;          // 2097152 sh
    short* kk     = qg + (size_t)BB * NN * C2;            // 2097152 sh
    short* vv     = kk + (size_t)BB * NN * C2;            // 2097152 sh
    float* Mpart  = (float*)(vv + (size_t)BB * NN * C2);  // 1048576 f

    k_prep<<<dim3(2048 + PM + CCH), dim3(256), 0, stream>>>(
        X, pe, Wq, bq, Wk, bk, Wv, bv, Wo, XpH, wpackh, bpack, Woh);
    k_projm<<<dim3(NN / 128, 3, BB), dim3(256), 0, stream>>>(
        XpH, tq, tk, tv, wpackh, bpack, qg, kk, vv);
    k_kv<<<dim3(KVS, BB), dim3(256), 0, stream>>>(kk, vv, Mpart);
    k_qmfinal<<<dim3(32, 2, BB), dim3(256), 0, stream>>>(qg, Mpart, Woh, X, out);
}